// Round 5
// baseline (84.890 us; speedup 1.0000x reference)
//
#include <hip/hip_runtime.h>

#define NTYPES 100
#define EMBED 64
#define N_BATCH 9000
#define ATOMS_PER_MOL 64
#define N_ATOMS (N_BATCH * ATOMS_PER_MOL)   // 576000
#define N4 (N_ATOMS / 4)                    // 144000 int4
#define TOTAL4 (N_ATOMS * 16)               // 9,216,000 float4 outputs
#define GRID 2048                           // 8 blocks/CU x 256 CUs = max waves, co-resident
#define BLOCK 256
#define NTHREADS (GRID * BLOCK)             // 524288
#define MARKERS 128                         // blocks that scan atom_types

// Single fused kernel: mark -> grid barrier -> rank LUT -> gather.
// R4 post-mortem: launch_bounds(256,4)+GRID=1024 halved occupancy (measured
// 48% in R3) and the gather chain (gld->lds->gld->st, ~500cyc) needs full
// occupancy to cover the 24.5 B/cyc/CU write roofline. This version runs at
// 8 blocks/CU (32 waves, the HW max) and unrolls the gather 2x.
// Coherent-point traffic stays tiny: 128 blocks x 4 atomicOr + 128 arrive
// adds (R3's 480us was 576K coherent stores; R4 fixed that).
__global__ __launch_bounds__(BLOCK, 8) void ae_fused(
        const int* __restrict__ atom_types,
        const float4* __restrict__ emb4,
        unsigned* __restrict__ bitmap,   // 4 words, zeroed by memset node
        int* __restrict__ arrive,        // zeroed by memset node
        float4* __restrict__ out4) {
    const int tid = threadIdx.x;
    __shared__ unsigned s_bm[4];
    __shared__ int s_rank[NTYPES];
    __shared__ int s_ok;

    if (tid < 4) s_bm[tid] = 0u;
    __syncthreads();

    // ---- Phase 1 (marker blocks only): presence bitmap ----
    if (blockIdx.x < MARKERS) {
        unsigned b0 = 0, b1 = 0, b2 = 0, b3 = 0;
        const int4* at4 = (const int4*)atom_types;
        for (int i = blockIdx.x * BLOCK + tid; i < N4; i += MARKERS * BLOCK) {
            int4 v = at4[i];
#define AE_SETBIT(t) { unsigned m = 1u << ((t) & 31); int j = (t) >> 5; \
            if (j == 0) b0 |= m; else if (j == 1) b1 |= m; \
            else if (j == 2) b2 |= m; else b3 |= m; }
            AE_SETBIT(v.x); AE_SETBIT(v.y); AE_SETBIT(v.z); AE_SETBIT(v.w);
#undef AE_SETBIT
        }
        for (int off = 32; off >= 1; off >>= 1) {   // 64-lane OR butterfly
            b0 |= __shfl_xor(b0, off);
            b1 |= __shfl_xor(b1, off);
            b2 |= __shfl_xor(b2, off);
            b3 |= __shfl_xor(b3, off);
        }
        if ((tid & 63) == 0) {                      // lane 0 of each wave
            atomicOr(&s_bm[0], b0);
            atomicOr(&s_bm[1], b1);
            atomicOr(&s_bm[2], b2);
            atomicOr(&s_bm[3], b3);
        }
        __syncthreads();
        if (tid < 4 && s_bm[tid]) atomicOr(&bitmap[tid], s_bm[tid]);
        __syncthreads();            // drains vmcnt: block's ORs done
        if (tid == 0) {
            __threadfence();        // release
            atomicAdd(arrive, 1);   // device-scope
        }
    }

    // ---- Phase 2: wait for all markers; publish bitmap to LDS ----
    if (tid == 0) {
        long long guard = 0;
        while (__hip_atomic_load(arrive, __ATOMIC_RELAXED,
                                 __HIP_MEMORY_SCOPE_AGENT) < MARKERS) {
            __builtin_amdgcn_s_sleep(32);
            if (++guard > 200000LL) break;          // ~0.17 s hang guard
        }
        s_ok = (guard <= 200000LL);
        if (s_ok) {
            __threadfence();        // acquire
            s_bm[0] = __hip_atomic_load(&bitmap[0], __ATOMIC_RELAXED, __HIP_MEMORY_SCOPE_AGENT);
            s_bm[1] = __hip_atomic_load(&bitmap[1], __ATOMIC_RELAXED, __HIP_MEMORY_SCOPE_AGENT);
            s_bm[2] = __hip_atomic_load(&bitmap[2], __ATOMIC_RELAXED, __HIP_MEMORY_SCOPE_AGENT);
            s_bm[3] = __hip_atomic_load(&bitmap[3], __ATOMIC_RELAXED, __HIP_MEMORY_SCOPE_AGENT);
        }
    }
    __syncthreads();

    // Fallback (never taken when co-resident): recompute bitmap locally.
    if (!s_ok) {
        if (tid < 4) s_bm[tid] = 0u;
        __syncthreads();
        unsigned b0 = 0, b1 = 0, b2 = 0, b3 = 0;
        const int4* at4 = (const int4*)atom_types;
        for (int i = tid; i < N4; i += BLOCK) {
            int4 v = at4[i];
#define AE_SETBIT(t) { unsigned m = 1u << ((t) & 31); int j = (t) >> 5; \
            if (j == 0) b0 |= m; else if (j == 1) b1 |= m; \
            else if (j == 2) b2 |= m; else b3 |= m; }
            AE_SETBIT(v.x); AE_SETBIT(v.y); AE_SETBIT(v.z); AE_SETBIT(v.w);
#undef AE_SETBIT
        }
        atomicOr(&s_bm[0], b0); atomicOr(&s_bm[1], b1);
        atomicOr(&s_bm[2], b2); atomicOr(&s_bm[3], b3);
        __syncthreads();
    }

    // ---- Phase 3: rank LUT. rank[t] = # set bits strictly below t ----
    if (tid < NTYPES) {
        int j = tid >> 5, b = tid & 31;
        int r = __popc(s_bm[j] & ((1u << b) - 1u));
        for (int k = 0; k < j; ++k) r += __popc(s_bm[k]);
        s_rank[tid] = r;
    }
    __syncthreads();

    // ---- Phase 4: gather, 2-way unrolled. 16 threads/atom, float4 stores ----
    const int gid = blockIdx.x * BLOCK + tid;
    const int q = gid & 15;                  // float4 slot (invariant mod NTHREADS)
    int g = gid;
    for (; g + NTHREADS < TOTAL4; g += 2 * NTHREADS) {
        int ta = atom_types[g >> 4];
        int tb = atom_types[(g + NTHREADS) >> 4];
        float4 va = emb4[s_rank[ta] * 16 + q];
        float4 vb = emb4[s_rank[tb] * 16 + q];
        out4[g] = va;
        out4[g + NTHREADS] = vb;
    }
    if (g < TOTAL4) {
        int t = atom_types[g >> 4];
        out4[g] = emb4[s_rank[t] * 16 + q];
    }
}

extern "C" void kernel_launch(void* const* d_in, const int* in_sizes, int n_in,
                              void* d_out, int out_size, void* d_ws, size_t ws_size,
                              hipStream_t stream) {
    const int* atom_types  = (const int*)d_in[0];    // [9000,64] int32
    const float* embedding = (const float*)d_in[1];  // [100,64]  f32
    float* out             = (float*)d_out;          // [9000,64,64] f32

    // ws layout: [0,16) bitmap[4] ; [16,20) arrive counter
    unsigned* bitmap = (unsigned*)d_ws;
    int* arrive      = (int*)((char*)d_ws + 16);

    // Node 0: zero bitmap + arrive (ws poisoned 0xAA, not re-poisoned between
    // replays; arrive would otherwise accumulate across calls).
    hipMemsetAsync(d_ws, 0, 64, stream);

    // Node 1: the whole op.
    ae_fused<<<GRID, BLOCK, 0, stream>>>(atom_types, (const float4*)embedding,
                                         bitmap, arrive, (float4*)out);
}

// Round 7
// 38.969 us; speedup vs baseline: 2.1784x; 2.1784x over previous
//
#include <hip/hip_runtime.h>

#define NTYPES 100
#define EMBED 64
#define N_BATCH 9000
#define ATOMS_PER_MOL 64
#define N_ATOMS (N_BATCH * ATOMS_PER_MOL)   // 576000
#define N4 (N_ATOMS / 4)                    // 144000 int4
#define TOTAL4 (N_ATOMS * 16)               // 9,216,000 float4 outputs
#define MBLK 64                             // marker blocks (one slot each)
#define MTHR 256
#define GBLK 2048                           // 8 blocks/CU x 256 CUs
#define GTHR 256
#define GSTRIDE (GBLK * GTHR)               // 524288

// Native clang vectors: __builtin_nontemporal_store requires these (HIP's
// HIP_vector_type wrapper class is rejected — R6 compile error).
typedef float  f32x4 __attribute__((ext_vector_type(4)));
typedef int    i32x4 __attribute__((ext_vector_type(4)));
typedef unsigned u32x4 __attribute__((ext_vector_type(4)));

// R5 post-mortem: intra-kernel spin barrier + device-scope fences burned
// ~60us (kernel 93us at 1.6TB/s with correct traffic & 83% occupancy ->
// stall was pre-gather phases; cost doubled with leader count R4->R5).
// Design: 2 dispatches, NO global atomics, NO memset. Cross-dispatch
// visibility of plain stores is guaranteed by the kernel-boundary release
// (proven by R2 passing with exactly this pattern).

// ---------------------------------------------------------------------------
// Node 0: each of 64 blocks writes its PARTIAL presence bitmap (128 bits)
// to its own 16B slot. Plain unconditional store -> poison-safe without
// zeroing, no coherent-point traffic.
// ---------------------------------------------------------------------------
__global__ __launch_bounds__(MTHR) void ae_mark(const i32x4* __restrict__ at4,
                                                u32x4* __restrict__ slots) {
    const int tid = threadIdx.x;
    __shared__ unsigned s_bm[4];
    if (tid < 4) s_bm[tid] = 0u;
    __syncthreads();

    unsigned b0 = 0, b1 = 0, b2 = 0, b3 = 0;
    for (int i = blockIdx.x * MTHR + tid; i < N4; i += MBLK * MTHR) {  // ~8.8 iters
        i32x4 v = at4[i];
#define AE_SETBIT(t) { unsigned m = 1u << ((t) & 31); int j = (t) >> 5; \
        if (j == 0) b0 |= m; else if (j == 1) b1 |= m; \
        else if (j == 2) b2 |= m; else b3 |= m; }
        AE_SETBIT(v.x); AE_SETBIT(v.y); AE_SETBIT(v.z); AE_SETBIT(v.w);
#undef AE_SETBIT
    }
    for (int off = 32; off >= 1; off >>= 1) {   // 64-lane OR butterfly
        b0 |= __shfl_xor(b0, off);
        b1 |= __shfl_xor(b1, off);
        b2 |= __shfl_xor(b2, off);
        b3 |= __shfl_xor(b3, off);
    }
    if ((tid & 63) == 0) {                      // lane 0 of each of 4 waves
        atomicOr(&s_bm[0], b0);                 // LDS atomics (cheap)
        atomicOr(&s_bm[1], b1);
        atomicOr(&s_bm[2], b2);
        atomicOr(&s_bm[3], b3);
    }
    __syncthreads();
    if (tid == 0) {
        u32x4 w; w.x = s_bm[0]; w.y = s_bm[1]; w.z = s_bm[2]; w.w = s_bm[3];
        slots[blockIdx.x] = w;                  // plain 16B store, own slot
    }
}

// ---------------------------------------------------------------------------
// Node 1: gather. Setup: wave 0 ORs the 64 slots (butterfly), then popcount
// rank LUT in LDS. Main loop: 16 threads/atom, 2-way unrolled, coalesced
// 16B/lane nontemporal stores (write-once 147MB shouldn't churn L2).
// ---------------------------------------------------------------------------
__global__ __launch_bounds__(GTHR) void ae_gather(
        const int* __restrict__ atom_types,
        const f32x4* __restrict__ emb4,
        const u32x4* __restrict__ slots,
        f32x4* __restrict__ out4) {
    const int tid = threadIdx.x;
    __shared__ unsigned s_bm[4];
    __shared__ int s_rank[NTYPES];

    if (tid < 64) {                             // wave 0 only
        u32x4 v = slots[tid];
        unsigned b0 = v.x, b1 = v.y, b2 = v.z, b3 = v.w;
        for (int off = 32; off >= 1; off >>= 1) {
            b0 |= __shfl_xor(b0, off);
            b1 |= __shfl_xor(b1, off);
            b2 |= __shfl_xor(b2, off);
            b3 |= __shfl_xor(b3, off);
        }
        if (tid == 0) { s_bm[0] = b0; s_bm[1] = b1; s_bm[2] = b2; s_bm[3] = b3; }
    }
    __syncthreads();

    if (tid < NTYPES) {                         // rank[t] = popcount(bits < t)
        int j = tid >> 5, b = tid & 31;
        int r = __popc(s_bm[j] & ((1u << b) - 1u));
        for (int k = 0; k < j; ++k) r += __popc(s_bm[k]);
        s_rank[tid] = r;
    }
    __syncthreads();

    const int gid = blockIdx.x * GTHR + tid;
    const int q = gid & 15;                     // float4 slot, invariant mod GSTRIDE
    int g = gid;
    for (; g + GSTRIDE < TOTAL4; g += 2 * GSTRIDE) {
        int ta = atom_types[g >> 4];
        int tb = atom_types[(g + GSTRIDE) >> 4];
        f32x4 va = emb4[s_rank[ta] * 16 + q];   // 25.6KB table, L1-resident
        f32x4 vb = emb4[s_rank[tb] * 16 + q];
        __builtin_nontemporal_store(va, &out4[g]);
        __builtin_nontemporal_store(vb, &out4[g + GSTRIDE]);
    }
    if (g < TOTAL4) {
        int t = atom_types[g >> 4];
        f32x4 v = emb4[s_rank[t] * 16 + q];
        __builtin_nontemporal_store(v, &out4[g]);
    }
}

extern "C" void kernel_launch(void* const* d_in, const int* in_sizes, int n_in,
                              void* d_out, int out_size, void* d_ws, size_t ws_size,
                              hipStream_t stream) {
    const int* atom_types  = (const int*)d_in[0];    // [9000,64] int32
    const float* embedding = (const float*)d_in[1];  // [100,64]  f32
    float* out             = (float*)d_out;          // [9000,64,64] f32

    u32x4* slots = (u32x4*)d_ws;   // 64 x 16B partial bitmaps (fully rewritten each call)

    ae_mark<<<MBLK, MTHR, 0, stream>>>((const i32x4*)atom_types, slots);
    ae_gather<<<GBLK, GTHR, 0, stream>>>(atom_types, (const f32x4*)embedding,
                                         slots, (f32x4*)out);
}

// Round 8
// 38.801 us; speedup vs baseline: 2.1878x; 1.0043x over previous
//
#include <hip/hip_runtime.h>

#define NTYPES 100
#define EMBED 64
#define N_BATCH 9000
#define ATOMS_PER_MOL 64
#define N_ATOMS (N_BATCH * ATOMS_PER_MOL)   // 576000
#define N4 (N_ATOMS / 4)                    // 144000 int4
#define TOTAL4 (N_ATOMS * 16)               // 9,216,000 float4 outputs
#define MBLK 64                             // marker blocks (one slot each)
#define MTHR 256
#define GBLK 2048                           // 8 blocks/CU x 256 CUs
#define GTHR 256
#define GSTRIDE (GBLK * GTHR)               // 524288

typedef float    f32x4 __attribute__((ext_vector_type(4)));
typedef int      i32x4 __attribute__((ext_vector_type(4)));
typedef unsigned u32x4 __attribute__((ext_vector_type(4)));

// R7 post-mortem: 2-node graph == 3-node graph time (39us) -> gaps are tiny,
// gather itself is ~33us (~4.5 TB/s) vs 6.5 TB/s fill calibration. A/B this
// round: nontemporal stores -> PLAIN stores (fills reach 6.5 with plain);
// gather unrolled 4-way (4 independent chains in flight per thread).

// ---------------------------------------------------------------------------
// Node 0: 64 blocks, each writes its PARTIAL presence bitmap (128 bits) to
// its own 16B slot. Plain unconditional store -> poison-safe, no atomics.
// Cross-dispatch visibility via kernel-boundary release (proven R2/R7).
// ---------------------------------------------------------------------------
__global__ __launch_bounds__(MTHR) void ae_mark(const i32x4* __restrict__ at4,
                                                u32x4* __restrict__ slots) {
    const int tid = threadIdx.x;
    __shared__ unsigned s_bm[4];
    if (tid < 4) s_bm[tid] = 0u;
    __syncthreads();

    unsigned b0 = 0, b1 = 0, b2 = 0, b3 = 0;
    for (int i = blockIdx.x * MTHR + tid; i < N4; i += MBLK * MTHR) {  // ~8.8 iters
        i32x4 v = at4[i];
#define AE_SETBIT(t) { unsigned m = 1u << ((t) & 31); int j = (t) >> 5; \
        if (j == 0) b0 |= m; else if (j == 1) b1 |= m; \
        else if (j == 2) b2 |= m; else b3 |= m; }
        AE_SETBIT(v.x); AE_SETBIT(v.y); AE_SETBIT(v.z); AE_SETBIT(v.w);
#undef AE_SETBIT
    }
    for (int off = 32; off >= 1; off >>= 1) {   // 64-lane OR butterfly
        b0 |= __shfl_xor(b0, off);
        b1 |= __shfl_xor(b1, off);
        b2 |= __shfl_xor(b2, off);
        b3 |= __shfl_xor(b3, off);
    }
    if ((tid & 63) == 0) {                      // lane 0 of each of 4 waves
        atomicOr(&s_bm[0], b0);                 // LDS atomics (cheap)
        atomicOr(&s_bm[1], b1);
        atomicOr(&s_bm[2], b2);
        atomicOr(&s_bm[3], b3);
    }
    __syncthreads();
    if (tid == 0) {
        u32x4 w; w.x = s_bm[0]; w.y = s_bm[1]; w.z = s_bm[2]; w.w = s_bm[3];
        slots[blockIdx.x] = w;                  // plain 16B store, own slot
    }
}

// ---------------------------------------------------------------------------
// Node 1: gather. Setup: wave 0 ORs the 64 slots, popcount rank LUT in LDS.
// Main loop: 16 threads/atom, 4-way unrolled, plain coalesced 16B/lane stores.
// ---------------------------------------------------------------------------
__global__ __launch_bounds__(GTHR) void ae_gather(
        const int* __restrict__ atom_types,
        const f32x4* __restrict__ emb4,
        const u32x4* __restrict__ slots,
        f32x4* __restrict__ out4) {
    const int tid = threadIdx.x;
    __shared__ unsigned s_bm[4];
    __shared__ int s_rank[NTYPES];

    if (tid < 64) {                             // wave 0 only
        u32x4 v = slots[tid];
        unsigned b0 = v.x, b1 = v.y, b2 = v.z, b3 = v.w;
        for (int off = 32; off >= 1; off >>= 1) {
            b0 |= __shfl_xor(b0, off);
            b1 |= __shfl_xor(b1, off);
            b2 |= __shfl_xor(b2, off);
            b3 |= __shfl_xor(b3, off);
        }
        if (tid == 0) { s_bm[0] = b0; s_bm[1] = b1; s_bm[2] = b2; s_bm[3] = b3; }
    }
    __syncthreads();

    if (tid < NTYPES) {                         // rank[t] = popcount(bits < t)
        int j = tid >> 5, b = tid & 31;
        int r = __popc(s_bm[j] & ((1u << b) - 1u));
        for (int k = 0; k < j; ++k) r += __popc(s_bm[k]);
        s_rank[tid] = r;
    }
    __syncthreads();

    const int gid = blockIdx.x * GTHR + tid;
    const int q = gid & 15;                     // float4 slot, invariant mod GSTRIDE
    int g = gid;
    // 4-way unroll: 4 independent load chains in flight, then 4 stores.
    for (; g + 3 * GSTRIDE < TOTAL4; g += 4 * GSTRIDE) {
        int t0 = atom_types[(g + 0 * GSTRIDE) >> 4];
        int t1 = atom_types[(g + 1 * GSTRIDE) >> 4];
        int t2 = atom_types[(g + 2 * GSTRIDE) >> 4];
        int t3 = atom_types[(g + 3 * GSTRIDE) >> 4];
        f32x4 v0 = emb4[s_rank[t0] * 16 + q];   // 25.6KB table, L1-resident
        f32x4 v1 = emb4[s_rank[t1] * 16 + q];
        f32x4 v2 = emb4[s_rank[t2] * 16 + q];
        f32x4 v3 = emb4[s_rank[t3] * 16 + q];
        out4[g + 0 * GSTRIDE] = v0;
        out4[g + 1 * GSTRIDE] = v1;
        out4[g + 2 * GSTRIDE] = v2;
        out4[g + 3 * GSTRIDE] = v3;
    }
    for (; g < TOTAL4; g += GSTRIDE) {
        int t = atom_types[g >> 4];
        out4[g] = emb4[s_rank[t] * 16 + q];
    }
}

extern "C" void kernel_launch(void* const* d_in, const int* in_sizes, int n_in,
                              void* d_out, int out_size, void* d_ws, size_t ws_size,
                              hipStream_t stream) {
    const int* atom_types  = (const int*)d_in[0];    // [9000,64] int32
    const float* embedding = (const float*)d_in[1];  // [100,64]  f32
    float* out             = (float*)d_out;          // [9000,64,64] f32

    u32x4* slots = (u32x4*)d_ws;   // 64 x 16B partial bitmaps (fully rewritten each call)

    ae_mark<<<MBLK, MTHR, 0, stream>>>((const i32x4*)atom_types, slots);
    ae_gather<<<GBLK, GTHR, 0, stream>>>(atom_types, (const f32x4*)embedding,
                                         slots, (f32x4*)out);
}